// Round 18
// baseline (95.142 us; speedup 1.0000x reference)
//
#include <hip/hip_runtime.h>
#include <math.h>

namespace {

constexpr int B_ = 4, N_ = 4, C_ = 64, H_ = 128, W_ = 128;
constexpr int HW_ = H_ * W_;

// out[:, 4] = ref
__global__ __launch_bounds__(256) void copyref_kernel(const float* __restrict__ ref,
                                                      float* __restrict__ out) {
    int t = blockIdx.x * 256 + threadIdx.x;      // one float4 per thread
    int f = t * 4;
    int b = f / (C_ * HW_);
    int within = f - b * (C_ * HW_);
    float4 v = *reinterpret_cast<const float4*>(ref + (size_t)b * C_ * HW_ + within);
    *reinterpret_cast<float4*>(out + (size_t)(b * 5 + N_) * C_ * HW_ + within) = v;
}

// ZERO-LDS / ZERO-BARRIER pure-gather kernel.
// 1 px/thread; block = 256 threads = 2 rows; grid = B*N*(H/2) = 1024 blocks
// (16 waves/CU). Each thread gathers its 3x3 window with 9 coalesced scalar
// loads per channel (lane x reads addr x-1/x/x+1 -> same cache lines shifted;
// L1/L2 serve the overlap). Window norms computed inline (9 FMA/ch) instead
// of shared via LDS -> no sync anywhere; waves free-run and the compiler can
// pipeline loads arbitrarily deep. Rounds 14-17 showed the barrier-windowed
// LDS structure was the ~70 us floor, not bandwidth/VALU/conflicts.
__global__ __launch_bounds__(256) void localcorr_kernel(const float* __restrict__ nbrs,
                                                        const float* __restrict__ ref,
                                                        float* __restrict__ out) {
    const int blk = blockIdx.x;          // 0..1023
    const int ypair = blk & 63;
    const int bi = blk >> 6;
    const int i = bi & 3;
    const int b = bi >> 2;
    const int t = (int)threadIdx.x;
    const int x = t & 127;
    const int ry = t >> 7;               // 0/1
    const int y = ypair * 2 + ry;

    // reflect-pad (np 'reflect', pad=1): -1 -> 1, 128 -> 126
    const int xm1 = (x == 0) ? 1 : x - 1;
    const int xp1 = (x == W_ - 1) ? W_ - 2 : x + 1;
    const int ym1 = (y == 0) ? 1 : y - 1;
    const int yp1 = (y == H_ - 1) ? H_ - 2 : y + 1;

    const int ro0 = ym1 * W_, ro1 = y * W_, ro2 = yp1 * W_;
    const int offR = y * W_ + x;

    const float* __restrict__ nb = nbrs + (size_t)(b * N_ + i) * C_ * HW_;
    const float* __restrict__ rp = ref + (size_t)b * C_ * HW_;

    float dot[9], nrm[9];
#pragma unroll
    for (int k = 0; k < 9; ++k) { dot[k] = 0.f; nrm[k] = 0.f; }
    float r2 = 0.f;

    // ---- pass 1: dots + window norms + ref2 (no sync, deep pipeline) ----
#pragma unroll 4
    for (int c = 0; c < C_; ++c) {
        const float* pc = nb + (size_t)c * HW_;
        const float w00 = pc[ro0 + xm1], w01 = pc[ro0 + x], w02 = pc[ro0 + xp1];
        const float w10 = pc[ro1 + xm1], w11 = pc[ro1 + x], w12 = pc[ro1 + xp1];
        const float w20 = pc[ro2 + xm1], w21 = pc[ro2 + x], w22 = pc[ro2 + xp1];
        const float rf = rp[(size_t)c * HW_ + offR];
        r2 += rf * rf;
        nrm[0] += w00 * w00; nrm[1] += w01 * w01; nrm[2] += w02 * w02;
        nrm[3] += w10 * w10; nrm[4] += w11 * w11; nrm[5] += w12 * w12;
        nrm[6] += w20 * w20; nrm[7] += w21 * w21; nrm[8] += w22 * w22;
        dot[0] += rf * w00; dot[1] += rf * w01; dot[2] += rf * w02;
        dot[3] += rf * w10; dot[4] += rf * w11; dot[5] += rf * w12;
        dot[6] += rf * w20; dot[7] += rf * w21; dot[8] += rf * w22;
    }

    // ---- softmax over 9 neighbors ----
    const float invr = rsqrtf(fmaxf(r2, 1e-24f));
    float iv[9], d[9];
#pragma unroll
    for (int k = 0; k < 9; ++k) {
        iv[k] = rsqrtf(fmaxf(nrm[k], 1e-24f));
        d[k] = dot[k] * invr * iv[k];
    }
    float mx = d[0];
#pragma unroll
    for (int k = 1; k < 9; ++k) mx = fmaxf(mx, d[k]);
    float ss = 0.f;
#pragma unroll
    for (int k = 0; k < 9; ++k) { d[k] = __expf(d[k] - mx); ss += d[k]; }
    const float is = 1.f / ss;
    float wtp[9];
#pragma unroll
    for (int k = 0; k < 9; ++k) wtp[k] = d[k] * is * iv[k];

    // ---- pass 2: aggregate + wdiff + store (no sync) ----
    const float* __restrict__ pm0 = nbrs + (size_t)(b * N_ + ((i + 1) & 3)) * C_ * HW_;
    const float* __restrict__ pm1 = nbrs + (size_t)(b * N_ + ((i + 2) & 3)) * C_ * HW_;
    const float* __restrict__ pm2 = nbrs + (size_t)(b * N_ + ((i + 3) & 3)) * C_ * HW_;
    float* __restrict__ op = out + (size_t)(b * 5 + i) * C_ * HW_ + offR;

#pragma unroll 4
    for (int c = 0; c < C_; ++c) {
        const float* pc = nb + (size_t)c * HW_;
        const float w00 = pc[ro0 + xm1], w01 = pc[ro0 + x], w02 = pc[ro0 + xp1];
        const float w10 = pc[ro1 + xm1], w11 = pc[ro1 + x], w12 = pc[ro1 + xp1];
        const float w20 = pc[ro2 + xm1], w21 = pc[ro2 + x], w22 = pc[ro2 + xp1];
        const float q0 = pm0[(size_t)c * HW_ + offR];
        const float q1 = pm1[(size_t)c * HW_ + offR];
        const float q2 = pm2[(size_t)c * HW_ + offR];
        const float agg = wtp[0] * w00 + wtp[1] * w01 + wtp[2] * w02
                        + wtp[3] * w10 + wtp[4] * w11 + wtp[5] * w12
                        + wtp[6] * w20 + wtp[7] * w21 + wtp[8] * w22;
        const float ctr = w11;
        const float dd = ctr - 0.25f * (ctr + q0 + q1 + q2);
        op[(size_t)c * HW_] = agg * __expf(-dd * dd);
    }
}

}  // namespace

extern "C" void kernel_launch(void* const* d_in, const int* in_sizes, int n_in,
                              void* d_out, int out_size, void* d_ws, size_t ws_size,
                              hipStream_t stream) {
    const float* nbrs = (const float*)d_in[0];
    const float* ref = (const float*)d_in[1];
    float* out = (float*)d_out;

    // slot 4 = ref copy
    copyref_kernel<<<(B_ * C_ * HW_ / 4) / 256, 256, 0, stream>>>(ref, out);

    // main: B*N*(H/2) = 1024 two-row blocks of 256 threads, no LDS, no barriers
    localcorr_kernel<<<B_ * N_ * (H_ / 2), 256, 0, stream>>>(nbrs, ref, out);
}

// Round 20
// 73.325 us; speedup vs baseline: 1.2975x; 1.2975x over previous
//
#include <hip/hip_runtime.h>
#include <math.h>

namespace {

constexpr int B_ = 4, N_ = 4, C_ = 64, H_ = 128, W_ = 128;
constexpr int HW_ = H_ * W_;
constexpr int CPB = 8;               // channels per barrier window (r19: 4 -> 8)
constexpr int NWIN = C_ / CPB;       // 8 windows per pass

// out[:, 4] = ref
__global__ __launch_bounds__(256) void copyref_kernel(const float* __restrict__ ref,
                                                      float* __restrict__ out) {
    int t = blockIdx.x * 256 + threadIdx.x;      // one float4 per thread
    int f = t * 4;
    int b = f / (C_ * HW_);
    int within = f - b * (C_ * HW_);
    float4 v = *reinterpret_cast<const float4*>(ref + (size_t)b * C_ * HW_ + within);
    *reinterpret_cast<float4*>(out + (size_t)(b * 5 + N_) * C_ * HW_ + within) = v;
}

// One thread per pixel; block = 2 rows (256 threads); full channel loop.
// Window norms = neighbor pixels' center norms, shared via LDS (stride-1 b32,
// proven conflict-free in r14/r17). CPB=8 channels per barrier window,
// double-buffered (16 slots): halves barrier count vs r14 and doubles the
// in-flight load depth per window (~1900 cy coverage vs ~900 cy HBM latency).
// r18 proved the staged structure beats pure gather (75 vs 114 us) — staging
// collapses 9 window reads into 3 coalesced loads + LDS.
__global__ __launch_bounds__(256) void localcorr_kernel(const float* __restrict__ nbrs,
                                                        const float* __restrict__ ref,
                                                        float* __restrict__ out) {
    __shared__ float s_own[2 * CPB][4][128];   // [slot][staged row][x] = 32 KB
    __shared__ float s_nrm[4][128];            // per-pixel sq-norms

    const int blk = blockIdx.x;          // 0..1023
    const int ypair = blk & 63;
    const int bi = blk >> 6;
    const int i = bi & 3;
    const int b = bi >> 2;
    const int t = (int)threadIdx.x;
    const int x = t & 127;
    const int ry = t >> 7;               // 0/1, wave-uniform
    const int y0 = ypair * 2;
    const int y = y0 + ry;

    // reflect-pad (np 'reflect', pad=1)
    const int xm = (x == 0) ? 1 : x - 1;
    const int xp = (x == W_ - 1) ? W_ - 2 : x + 1;
    const int gyA = (y0 == 0) ? 1 : y0 - 1;
    const int gyC = y0 + 1;
    const int gyD = (y0 + 2 == H_) ? H_ - 2 : y0 + 2;
    const int myRowA = (ry == 0) ? gyA : gyC;   // staged row 2ry
    const int myRowB = (ry == 0) ? y0 : gyD;    // staged row 2ry+1

    const float* __restrict__ nb = nbrs + (size_t)(b * N_ + i) * C_ * HW_;
    const float* __restrict__ rp = ref + (size_t)b * C_ * HW_;
    const int offA = myRowA * W_ + x;
    const int offB = myRowB * W_ + x;
    const int offR = y * W_ + x;

    float dot[9];
#pragma unroll
    for (int k = 0; k < 9; ++k) dot[k] = 0.f;
    float nA = 0.f, nB = 0.f, r2 = 0.f;

    // ---- pass 1: dots + norms + ref2 ----
    float co0[CPB], co1[CPB], crf[CPB];
    float no0[CPB], no1[CPB], nrf[CPB];
#pragma unroll
    for (int u = 0; u < CPB; ++u) {
        const size_t co = (size_t)u * HW_;
        co0[u] = nb[co + offA]; co1[u] = nb[co + offB]; crf[u] = rp[co + offR];
    }
#pragma unroll 1
    for (int w = 0; w < NWIN; ++w) {
        const int base = (w & 1) * CPB;
#pragma unroll
        for (int u = 0; u < CPB; ++u) {
            s_own[base + u][2 * ry + 0][x] = co0[u];
            s_own[base + u][2 * ry + 1][x] = co1[u];
        }
        if (w + 1 < NWIN) {
#pragma unroll
            for (int u = 0; u < CPB; ++u) {
                const size_t co = (size_t)((w + 1) * CPB + u) * HW_;
                no0[u] = nb[co + offA]; no1[u] = nb[co + offB]; nrf[u] = rp[co + offR];
            }
        }
        __syncthreads();
#pragma unroll
        for (int u = 0; u < CPB; ++u) {
            const float w00 = s_own[base + u][ry + 0][xm], w02 = s_own[base + u][ry + 0][xp];
            const float w10 = s_own[base + u][ry + 1][xm], w12 = s_own[base + u][ry + 1][xp];
            const float w20 = s_own[base + u][ry + 2][xm], w22 = s_own[base + u][ry + 2][xp];
            float w01, w11, w21;
            if (ry == 0) { w01 = co0[u]; w11 = co1[u]; w21 = s_own[base + u][2][x]; }
            else         { w01 = s_own[base + u][1][x]; w11 = co0[u]; w21 = co1[u]; }
            const float rf = crf[u];
            nA += co0[u] * co0[u]; nB += co1[u] * co1[u]; r2 += rf * rf;
            dot[0] += rf * w00; dot[1] += rf * w01; dot[2] += rf * w02;
            dot[3] += rf * w10; dot[4] += rf * w11; dot[5] += rf * w12;
            dot[6] += rf * w20; dot[7] += rf * w21; dot[8] += rf * w22;
        }
#pragma unroll
        for (int u = 0; u < CPB; ++u) { co0[u] = no0[u]; co1[u] = no1[u]; crf[u] = nrf[u]; }
    }

    // ---- share norms, softmax in-register ----
    s_nrm[2 * ry + 0][x] = nA;
    s_nrm[2 * ry + 1][x] = nB;
    __syncthreads();
    float nk[9];
    nk[0] = s_nrm[ry + 0][xm]; nk[1] = s_nrm[ry + 0][x]; nk[2] = s_nrm[ry + 0][xp];
    nk[3] = s_nrm[ry + 1][xm]; nk[4] = s_nrm[ry + 1][x]; nk[5] = s_nrm[ry + 1][xp];
    nk[6] = s_nrm[ry + 2][xm]; nk[7] = s_nrm[ry + 2][x]; nk[8] = s_nrm[ry + 2][xp];

    const float invr = rsqrtf(fmaxf(r2, 1e-24f));
    float inv[9], d[9];
#pragma unroll
    for (int k = 0; k < 9; ++k) {
        inv[k] = rsqrtf(fmaxf(nk[k], 1e-24f));
        d[k] = dot[k] * invr * inv[k];
    }
    float mx = d[0];
#pragma unroll
    for (int k = 1; k < 9; ++k) mx = fmaxf(mx, d[k]);
    float ssum = 0.f;
#pragma unroll
    for (int k = 0; k < 9; ++k) { d[k] = __expf(d[k] - mx); ssum += d[k]; }
    const float is = 1.f / ssum;
    float wtp[9];
#pragma unroll
    for (int k = 0; k < 9; ++k) wtp[k] = d[k] * is * inv[k];

    // ---- pass 2: aggregate + wdiff + store ----
    const float* __restrict__ pm0 = nbrs + (size_t)(b * N_ + ((i + 1) & 3)) * C_ * HW_;
    const float* __restrict__ pm1 = nbrs + (size_t)(b * N_ + ((i + 2) & 3)) * C_ * HW_;
    const float* __restrict__ pm2 = nbrs + (size_t)(b * N_ + ((i + 3) & 3)) * C_ * HW_;
    float* __restrict__ op = out + (size_t)(b * 5 + i) * C_ * HW_ + offR;

    float q0c[CPB], q1c[CPB], q2c[CPB];
    float q0n[CPB], q1n[CPB], q2n[CPB];
#pragma unroll
    for (int u = 0; u < CPB; ++u) {
        const size_t co = (size_t)u * HW_;
        co0[u] = nb[co + offA]; co1[u] = nb[co + offB];
        q0c[u] = pm0[co + offR]; q1c[u] = pm1[co + offR]; q2c[u] = pm2[co + offR];
    }
#pragma unroll 1
    for (int w = 0; w < NWIN; ++w) {
        const int base = (w & 1) * CPB;
#pragma unroll
        for (int u = 0; u < CPB; ++u) {
            s_own[base + u][2 * ry + 0][x] = co0[u];
            s_own[base + u][2 * ry + 1][x] = co1[u];
        }
        if (w + 1 < NWIN) {
#pragma unroll
            for (int u = 0; u < CPB; ++u) {
                const size_t co = (size_t)((w + 1) * CPB + u) * HW_;
                no0[u] = nb[co + offA]; no1[u] = nb[co + offB];
                q0n[u] = pm0[co + offR]; q1n[u] = pm1[co + offR]; q2n[u] = pm2[co + offR];
            }
        }
        __syncthreads();
#pragma unroll
        for (int u = 0; u < CPB; ++u) {
            const float w00 = s_own[base + u][ry + 0][xm], w02 = s_own[base + u][ry + 0][xp];
            const float w10 = s_own[base + u][ry + 1][xm], w12 = s_own[base + u][ry + 1][xp];
            const float w20 = s_own[base + u][ry + 2][xm], w22 = s_own[base + u][ry + 2][xp];
            float w01, w11, w21;
            if (ry == 0) { w01 = co0[u]; w11 = co1[u]; w21 = s_own[base + u][2][x]; }
            else         { w01 = s_own[base + u][1][x]; w11 = co0[u]; w21 = co1[u]; }
            const float agg = wtp[0] * w00 + wtp[1] * w01 + wtp[2] * w02
                            + wtp[3] * w10 + wtp[4] * w11 + wtp[5] * w12
                            + wtp[6] * w20 + wtp[7] * w21 + wtp[8] * w22;
            const float ctr = w11;
            const float dd = ctr - 0.25f * (ctr + q0c[u] + q1c[u] + q2c[u]);
            op[(size_t)(w * CPB + u) * HW_] = agg * __expf(-dd * dd);
        }
#pragma unroll
        for (int u = 0; u < CPB; ++u) {
            co0[u] = no0[u]; co1[u] = no1[u];
            q0c[u] = q0n[u]; q1c[u] = q1n[u]; q2c[u] = q2n[u];
        }
    }
}

}  // namespace

extern "C" void kernel_launch(void* const* d_in, const int* in_sizes, int n_in,
                              void* d_out, int out_size, void* d_ws, size_t ws_size,
                              hipStream_t stream) {
    const float* nbrs = (const float*)d_in[0];
    const float* ref = (const float*)d_in[1];
    float* out = (float*)d_out;

    // slot 4 = ref copy
    copyref_kernel<<<(B_ * C_ * HW_ / 4) / 256, 256, 0, stream>>>(ref, out);

    // main: B*N*(H/2) = 1024 two-row blocks of 256 threads
    localcorr_kernel<<<B_ * N_ * (H_ / 2), 256, 0, stream>>>(nbrs, ref, out);
}